// Round 6
// baseline (6408.495 us; speedup 1.0000x reference)
//
#include <hip/hip_runtime.h>

#define SEQ 512
#define BB 64
#define IN_DIM 128
#define HH 256
#define NL 6
#define G3 768
#define KT 16            // K tiles of 32 -> K=512 (layer0 pads tail with zeros)
#define SA 520           // padded LDS stride in bf16 elems
#define CUS_PER_LAYER 16
#define JPC 16
#define FSTRIDE 16       // ints per flag (64B)
#define HD 2             // h-ring depth
#define FD 4             // forward-ring depth
#define RING_ELEMS (BB*HH)

typedef short short8 __attribute__((ext_vector_type(8)));
typedef short short4v __attribute__((ext_vector_type(4)));
typedef float f32x4 __attribute__((ext_vector_type(4)));

// ws layout: hring[NL][HD][BB][HH] bf16 | fring[NL-1][FD][BB][HH] bf16 | flags
#define FRING_OFF_SH (NL*HD*RING_ELEMS)
#define FLAGS_OFF_B  ((FRING_OFF_SH + (NL-1)*FD*RING_ELEMS)*2)
#define NFLAG_INTS   (16 + 3*NL*(SEQ+1)*FSTRIDE)

__device__ __forceinline__ short f2bf(float f) {
    unsigned u = __builtin_bit_cast(unsigned, f);
    u += 0x7fffu + ((u >> 16) & 1u);
    return (short)(u >> 16);
}
__device__ __forceinline__ float sigm(float v) { return __fdividef(1.f, 1.f + __expf(-v)); }
__device__ __forceinline__ float tanh_f(float v) { float e = __expf(2.f * v); return 1.f - __fdividef(2.f, e + 1.f); }

// R2-proven protocol: relaxed agent polls (cheap) + one acquire fence on success.
__device__ __forceinline__ void spin_ac(int* p, int target, unsigned long long ddl) {
    for (;;) {
        if (__hip_atomic_load(p, __ATOMIC_RELAXED, __HIP_MEMORY_SCOPE_AGENT) >= target) break;
        __builtin_amdgcn_s_sleep(4);
        if (__builtin_amdgcn_s_memrealtime() > ddl) break;   // fail-visible, no hang
    }
    __builtin_amdgcn_fence(__ATOMIC_ACQUIRE, "agent");
}
__device__ __forceinline__ void rel_inc(int* p) {
    __hip_atomic_fetch_add(p, 1, __ATOMIC_RELEASE, __HIP_MEMORY_SCOPE_AGENT);
}

__global__ __launch_bounds__(256, 1) void gru_persist(
    const float* __restrict__ x, const float* __restrict__ h0,
    const float* __restrict__ w_ih0, const float* __restrict__ w_ih_rest,
    const float* __restrict__ w_hh, const float* __restrict__ b_ih,
    const float* __restrict__ b_hh, float* __restrict__ y,
    short* __restrict__ hring, short* __restrict__ fring, int* __restrict__ flags)
{
    extern __shared__ char dynpad[];   // pushes LDS use past 80KB -> 1 WG/CU
    (void)dynpad;

    const int tid = threadIdx.x;
    const unsigned long long ddl = __builtin_amdgcn_s_memrealtime() + 1000000000ull; // ~10s

    // ---- physical placement: layer = XCC_ID, slot = per-XCD ticket ----
    const int xcc = __builtin_amdgcn_s_getreg(20 | (31 << 11)) & 0xf;  // HW_REG_XCC_ID
    if (xcc >= NL) return;
    __shared__ int s_slot;
    if (tid == 0) s_slot = __hip_atomic_fetch_add(&flags[xcc], 1, __ATOMIC_RELAXED, __HIP_MEMORY_SCOPE_AGENT);
    __syncthreads();
    const int slot = s_slot;
    if (slot >= CUS_PER_LAYER) return;

    const int l = xcc;
    const int jbase = slot * JPC;
    const int lane = tid & 63;
    const int wave = tid >> 6;
    const int q = lane >> 4;
    const int jj = lane & 15;
    const int jrow = jbase + jj;

    int* hflag = flags + 16;
    int* fflag = hflag + NL * (SEQ + 1) * FSTRIDE;
    int* cflag = fflag + NL * (SEQ + 1) * FSTRIDE;
    #define HF(L,I) (hflag + ((L)*(SEQ+1)+(I))*FSTRIDE)
    #define FF(L,I) (fflag + ((L)*(SEQ+1)+(I))*FSTRIDE)
    #define CF(L,I) (cflag + ((L)*(SEQ+1)+(I))*FSTRIDE)

    __shared__ short sAm[64 * SA];   // activations [b][k] bf16
    __shared__ float sH[64 * 17];    // fp32 h slice [b][jj]

    // ---- h0 init: fp32 to LDS + bf16 to hring slot 1 (slot for t=-1) ----
    short* ring_init = hring + (l * HD + 1) * RING_ELEMS;
    for (int i = tid; i < BB * JPC; i += 256) {
        int b = i >> 4, j2 = i & 15;
        float v = h0[(size_t)l * BB * HH + b * HH + jbase + j2];
        sH[b * 17 + j2] = v;
        ring_init[b * HH + jbase + j2] = f2bf(v);
    }
    __syncthreads();                 // all waves' stores drained (vmcnt 0 at barrier)
    if (tid == 0) rel_inc(HF(l, 0));

    // zero layer-0 activation tail cols [384,512) once
    if (l == 0) {
        short8 z8 = {};
        for (int i = tid; i < 64 * 16; i += 256) {
            int row = i >> 4, c8 = (i & 15) * 8;
            *reinterpret_cast<short8*>(&sAm[row * SA + 384 + c8]) = z8;
        }
    }

    // ---- weight preload into registers (bf16 B-fragments) ----
    const int KIN = (l == 0) ? IN_DIM : HH;
    const float* wih = (l == 0) ? w_ih0 : (w_ih_rest + (size_t)(l - 1) * G3 * HH);
    const float* whh = w_hh + (size_t)l * G3 * HH;
    const int kq = q * 8;
    short8 Breg[3 * KT];
    #pragma unroll
    for (int g = 0; g < 3; ++g) {
        const int row = g * HH + jrow;
        #pragma unroll
        for (int kt = 0; kt < KT; ++kt) {
            int k = kt * 32 + kq;
            short8 v = {};
            const float* p = nullptr;
            if (k < KIN)            p = wih + (size_t)row * KIN + k;
            else if (k < KIN + HH)  p = whh + (size_t)row * HH + (k - KIN);
            if (p) {
                float4 a = *(const float4*)p;
                float4 c = *(const float4*)(p + 4);
                v[0] = f2bf(a.x); v[1] = f2bf(a.y); v[2] = f2bf(a.z); v[3] = f2bf(a.w);
                v[4] = f2bf(c.x); v[5] = f2bf(c.y); v[6] = f2bf(c.z); v[7] = f2bf(c.w);
            }
            Breg[g * KT + kt] = v;
        }
    }
    const float bsr = b_ih[l * G3 + jrow] + b_hh[l * G3 + jrow];
    const float bsz = b_ih[l * G3 + HH + jrow] + b_hh[l * G3 + HH + jrow];
    const float bin_ = b_ih[l * G3 + 2 * HH + jrow];
    const float bhn_ = b_hh[l * G3 + 2 * HH + jrow];

    const int ksplit = (l == 0) ? 4 : 8;
    const int Mbase = wave * 16;
    const int aoff = (Mbase + jj) * SA + kq;

    for (int t = 0; t < SEQ; ++t) {
        // ---- parallel waits on 3 waves (R2-proven primitives) ----
        if (tid == 0)                            spin_ac(HF(l, t), CUS_PER_LAYER, ddl);
        if (l > 0 && tid == 64)                  spin_ac(FF(l - 1, t), CUS_PER_LAYER, ddl);
        if (l < NL - 1 && t >= FD && tid == 128) spin_ac(CF(l + 1, t - FD), CUS_PER_LAYER, ddl);
        __syncthreads();

        // ---- stage activations into LDS [b][k] (plain loads, acquire-guarded) ----
        {
            const short8* ph = (const short8*)((const char*)(hring + (l * HD + ((t + 1) & 1)) * RING_ELEMS) + tid * 128);
            short8 h0v = ph[0], h1v = ph[1], h2v = ph[2], h3v = ph[3];
            short8 h4v = ph[4], h5v = ph[5], h6v = ph[6], h7v = ph[7];
            short* dh = &sAm[(tid >> 2) * SA + KIN + (tid & 3) * 64];
            if (l == 0) {
                const float* xt = x + (size_t)t * BB * IN_DIM;
                #pragma unroll
                for (int i = 0; i < 8; ++i) {
                    int c = tid + i * 256;
                    int row = c >> 5, col = (c & 31) * 4;
                    float4 vv = *(const float4*)(xt + row * IN_DIM + col);
                    short4v s;
                    s[0] = f2bf(vv.x); s[1] = f2bf(vv.y); s[2] = f2bf(vv.z); s[3] = f2bf(vv.w);
                    *reinterpret_cast<short4v*>(&sAm[row * SA + col]) = s;
                }
            } else {
                const short8* pf = (const short8*)((const char*)(fring + ((l - 1) * FD + (t & 3)) * RING_ELEMS) + tid * 128);
                short8 w0 = pf[0], w1 = pf[1], w2 = pf[2], w3 = pf[3];
                short8 w4 = pf[4], w5 = pf[5], w6 = pf[6], w7 = pf[7];
                short* dx = &sAm[(tid >> 2) * SA + (tid & 3) * 64];
                *(short8*)(dx + 0)  = w0; *(short8*)(dx + 8)  = w1;
                *(short8*)(dx + 16) = w2; *(short8*)(dx + 24) = w3;
                *(short8*)(dx + 32) = w4; *(short8*)(dx + 40) = w5;
                *(short8*)(dx + 48) = w6; *(short8*)(dx + 56) = w7;
            }
            *(short8*)(dh + 0)  = h0v; *(short8*)(dh + 8)  = h1v;
            *(short8*)(dh + 16) = h2v; *(short8*)(dh + 24) = h3v;
            *(short8*)(dh + 32) = h4v; *(short8*)(dh + 40) = h5v;
            *(short8*)(dh + 48) = h6v; *(short8*)(dh + 56) = h7v;
        }
        __syncthreads();

        // ---- MFMA ----
        f32x4 ax0 = {}, ax1 = {}, ax2 = {}, ah0 = {}, ah1 = {}, ah2 = {};
        #pragma unroll
        for (int kt = 0; kt < KT; ++kt) {
            short8 a = *reinterpret_cast<const short8*>(&sAm[aoff + kt * 32]);
            if (kt < ksplit) {
                ax0 = __builtin_amdgcn_mfma_f32_16x16x32_bf16(a, Breg[0 * KT + kt], ax0, 0, 0, 0);
                ax1 = __builtin_amdgcn_mfma_f32_16x16x32_bf16(a, Breg[1 * KT + kt], ax1, 0, 0, 0);
                ax2 = __builtin_amdgcn_mfma_f32_16x16x32_bf16(a, Breg[2 * KT + kt], ax2, 0, 0, 0);
            } else {
                ah0 = __builtin_amdgcn_mfma_f32_16x16x32_bf16(a, Breg[0 * KT + kt], ah0, 0, 0, 0);
                ah1 = __builtin_amdgcn_mfma_f32_16x16x32_bf16(a, Breg[1 * KT + kt], ah1, 0, 0, 0);
                ah2 = __builtin_amdgcn_mfma_f32_16x16x32_bf16(a, Breg[2 * KT + kt], ah2, 0, 0, 0);
            }
        }

        // ---- gates + plain stores; release fence (in rel_inc) publishes them ----
        short* hdst = hring + (l * HD + (t & 1)) * RING_ELEMS;
        short* fdst = fring + (l * FD + (t & 3)) * RING_ELEMS;   // used only l<5
        float* ydst = y + (size_t)t * BB * HH;
        #pragma unroll
        for (int r = 0; r < 4; ++r) {
            int b = Mbase + 4 * q + r;
            float ho = sH[b * 17 + jj];
            float rg = sigm(ax0[r] + ah0[r] + bsr);
            float zg = sigm(ax1[r] + ah1[r] + bsz);
            float ng = tanh_f(ax2[r] + bin_ + rg * (ah2[r] + bhn_));
            float hn = ng + zg * (ho - ng);
            sH[b * 17 + jj] = hn;
            short hb = f2bf(hn);
            hdst[b * HH + jrow] = hb;
            if (l < NL - 1) fdst[b * HH + jrow] = hb;
            else            ydst[b * HH + jrow] = hn;
        }
        __syncthreads();                 // every wave drains vmcnt before barrier
        if (tid == 0)               rel_inc(HF(l, t + 1));
        if (l < NL - 1 && tid == 64) rel_inc(FF(l, t));
        if (l > 0 && tid == 128)     rel_inc(CF(l, t));
    }

    // ---- final hidden states (fp32 from LDS) ----
    for (int i = tid; i < BB * JPC; i += 256) {
        int b = i >> 4, j2 = i & 15;
        y[(size_t)SEQ * BB * HH + (size_t)l * BB * HH + b * HH + jbase + j2] = sH[b * 17 + j2];
    }
}

extern "C" void kernel_launch(void* const* d_in, const int* in_sizes, int n_in,
                              void* d_out, int out_size, void* d_ws, size_t ws_size,
                              hipStream_t stream) {
    (void)in_sizes; (void)n_in; (void)out_size; (void)ws_size;
    const float* x         = (const float*)d_in[0];
    const float* h0        = (const float*)d_in[1];
    const float* w_ih0     = (const float*)d_in[2];
    const float* w_ih_rest = (const float*)d_in[3];
    const float* w_hh      = (const float*)d_in[4];
    const float* b_ih      = (const float*)d_in[5];
    const float* b_hh      = (const float*)d_in[6];
    float* y = (float*)d_out;

    short* hring = (short*)d_ws;
    short* fring = hring + FRING_OFF_SH;
    int* flags   = (int*)((char*)d_ws + FLAGS_OFF_B);

    (void)hipMemsetAsync(flags, 0, NFLAG_INTS * sizeof(int), stream);
    // static(~69KB) + dynamic 16KB LDS > 80KB -> exactly 1 WG per CU
    gru_persist<<<256, 256, 16384, stream>>>(
        x, h0, w_ih0, w_ih_rest, w_hh, b_ih, b_hh, y, hring, fring, flags);
}

// Round 7
// 4630.098 us; speedup vs baseline: 1.3841x; 1.3841x over previous
//
#include <hip/hip_runtime.h>

#define SEQ 512
#define BB 64
#define IN_DIM 128
#define HH 256
#define NL 6
#define G3 768
#define KT 16            // K tiles of 32 -> K=512 (layer0 pads tail with zeros)
#define SA 520           // padded LDS stride in bf16 elems
#define CUS_PER_LAYER 16
#define JPC 16
#define RD 4             // unified ring depth
#define RING_ELEMS (BB*HH)

typedef short short8 __attribute__((ext_vector_type(8)));
typedef short short4v __attribute__((ext_vector_type(4)));
typedef float f32x4 __attribute__((ext_vector_type(4)));

// ws layout: ring[NL][RD][BB][HH] bf16 | seq[NL][16] int | tickets[8] int
#define FLAGS_OFF_B (NL*RD*RING_ELEMS*2)      // 786432
#define NFLAG_INTS  (NL*16 + 16)

__device__ __forceinline__ short f2bf(float f) {
    unsigned u = __builtin_bit_cast(unsigned, f);
    u += 0x7fffu + ((u >> 16) & 1u);   // RNE
    return (short)(u >> 16);
}
__device__ __forceinline__ float sigm(float v) { return __fdividef(1.f, 1.f + __expf(-v)); }
__device__ __forceinline__ float tanh_f(float v) { float e = __expf(2.f * v); return 1.f - __fdividef(2.f, e + 1.f); }

__global__ __launch_bounds__(256, 1) void gru_persist(
    const float* __restrict__ x, const float* __restrict__ h0,
    const float* __restrict__ w_ih0, const float* __restrict__ w_ih_rest,
    const float* __restrict__ w_hh, const float* __restrict__ b_ih,
    const float* __restrict__ b_hh, float* __restrict__ y,
    short* __restrict__ ring, int* __restrict__ flags)
{
    extern __shared__ char dynpad[];   // pushes LDS use past 80KB -> 1 WG/CU
    (void)dynpad;

    const int tid = threadIdx.x;
    const unsigned long long ddl = __builtin_amdgcn_s_memrealtime() + 1000000000ull; // ~10s

    // ---- physical placement: layer = XCC_ID, slot = per-XCD ticket ----
    const int xcc = __builtin_amdgcn_s_getreg(20 | (31 << 11)) & 0xf;  // HW_REG_XCC_ID
    if (xcc >= NL) return;
    __shared__ int s_slot;
    int* tickets = flags + NL * 16;
    if (tid == 0) s_slot = __hip_atomic_fetch_add(&tickets[xcc], 1, __ATOMIC_RELAXED, __HIP_MEMORY_SCOPE_AGENT);
    __syncthreads();
    const int slot = s_slot;
    if (slot >= CUS_PER_LAYER) return;

    const int l = xcc;
    const int jbase = slot * JPC;
    const int lane = tid & 63;
    const int wave = tid >> 6;
    const int q = lane >> 4;
    const int jj = lane & 15;
    const int jrow = jbase + jj;

    #define SQF(L) (flags + (L) * 16)

    __shared__ short sAm[64 * SA];   // activations [b][k] bf16
    __shared__ float sH[64 * 17];    // fp32 h slice [b][jj]

    // ---- h0 init: fp32 to LDS + bf16 to ring slot 3 (holds y(-1)) ----
    short* ring_init = ring + (l * RD + 3) * RING_ELEMS;
    for (int i = tid; i < BB * JPC; i += 256) {
        int b = i >> 4, j2 = i & 15;
        float v = h0[(size_t)l * BB * HH + b * HH + jbase + j2];
        sH[b * 17 + j2] = v;
        ring_init[b * HH + jbase + j2] = f2bf(v);
    }
    __syncthreads();                 // all waves drain stores before publish
    if (tid == 0)
        __hip_atomic_store(&SQF(l)[slot], 1, __ATOMIC_RELEASE, __HIP_MEMORY_SCOPE_AGENT);

    // zero layer-0 activation tail cols [384,512) once
    if (l == 0) {
        short8 z8 = {};
        for (int i = tid; i < 64 * 16; i += 256) {
            int row = i >> 4, c8 = (i & 15) * 8;
            *reinterpret_cast<short8*>(&sAm[row * SA + 384 + c8]) = z8;
        }
    }

    // ---- weight preload into registers (bf16 B-fragments) ----
    const int KIN = (l == 0) ? IN_DIM : HH;
    const float* wih = (l == 0) ? w_ih0 : (w_ih_rest + (size_t)(l - 1) * G3 * HH);
    const float* whh = w_hh + (size_t)l * G3 * HH;
    const int kq = q * 8;
    short8 Breg[3 * KT];
    #pragma unroll
    for (int g = 0; g < 3; ++g) {
        const int row = g * HH + jrow;
        #pragma unroll
        for (int kt = 0; kt < KT; ++kt) {
            int k = kt * 32 + kq;
            short8 v = {};
            const float* p = nullptr;
            if (k < KIN)            p = wih + (size_t)row * KIN + k;
            else if (k < KIN + HH)  p = whh + (size_t)row * HH + (k - KIN);
            if (p) {
                float4 a = *(const float4*)p;
                float4 c = *(const float4*)(p + 4);
                v[0] = f2bf(a.x); v[1] = f2bf(a.y); v[2] = f2bf(a.z); v[3] = f2bf(a.w);
                v[4] = f2bf(c.x); v[5] = f2bf(c.y); v[6] = f2bf(c.z); v[7] = f2bf(c.w);
            }
            Breg[g * KT + kt] = v;
        }
    }
    const float bsr = b_ih[l * G3 + jrow] + b_hh[l * G3 + jrow];
    const float bsz = b_ih[l * G3 + HH + jrow] + b_hh[l * G3 + HH + jrow];
    const float bin_ = b_ih[l * G3 + 2 * HH + jrow];
    const float bhn_ = b_hh[l * G3 + 2 * HH + jrow];

    const int ksplit = (l == 0) ? 4 : 8;
    const int Mbase = wave * 16;
    const int aoff = (Mbase + jj) * SA + kq;

    // poll-wave setup (wave 0): lanes 0-15 own, 16-31 prev, 32-47 next
    int* paddr = SQF(l) + jj;
    bool pactive = false;
    int tshift = 0;                  // target = t + tshift
    if (wave == 0) {
        if (q == 0)      { paddr = SQF(l) + jj;     tshift = 1;  pactive = true; }
        else if (q == 1) { if (l > 0)      { paddr = SQF(l - 1) + jj; tshift = 2;  pactive = true; } }
        else if (q == 2) { if (l < NL - 1) { paddr = SQF(l + 1) + jj; tshift = -2; pactive = true; } }
    }

    for (int t = 0; t < SEQ; ++t) {
        // ---- one-wave combined poll: 48 relaxed loads/round + 1 acquire fence ----
        if (wave == 0) {
            const int target = t + tshift;
            int iter = 0;
            for (;;) {
                int v = __hip_atomic_load(paddr, __ATOMIC_RELAXED, __HIP_MEMORY_SCOPE_AGENT);
                bool ok = (!pactive) || (v >= target);
                if (__ballot(ok) == 0xFFFFFFFFFFFFFFFFull) break;
                if (((++iter) & 63) == 0 && __builtin_amdgcn_s_memrealtime() > ddl) break;
            }
            __builtin_amdgcn_fence(__ATOMIC_ACQUIRE, "agent");
        }
        __syncthreads();

        // ---- stage activations into LDS [b][k] ----
        {
            const short8* ph = (const short8*)((const char*)(ring + (l * RD + ((t + 3) & 3)) * RING_ELEMS) + tid * 128);
            short8 h0v = ph[0], h1v = ph[1], h2v = ph[2], h3v = ph[3];
            short8 h4v = ph[4], h5v = ph[5], h6v = ph[6], h7v = ph[7];
            short* dh = &sAm[(tid >> 2) * SA + KIN + (tid & 3) * 64];
            if (l == 0) {
                const float* xt = x + (size_t)t * BB * IN_DIM;
                #pragma unroll
                for (int i = 0; i < 8; ++i) {
                    int c = tid + i * 256;
                    int row = c >> 5, col = (c & 31) * 4;
                    float4 vv = *(const float4*)(xt + row * IN_DIM + col);
                    short4v s;
                    s[0] = f2bf(vv.x); s[1] = f2bf(vv.y); s[2] = f2bf(vv.z); s[3] = f2bf(vv.w);
                    *reinterpret_cast<short4v*>(&sAm[row * SA + col]) = s;
                }
            } else {
                const short8* pf = (const short8*)((const char*)(ring + ((l - 1) * RD + (t & 3)) * RING_ELEMS) + tid * 128);
                short8 w0 = pf[0], w1 = pf[1], w2 = pf[2], w3 = pf[3];
                short8 w4 = pf[4], w5 = pf[5], w6 = pf[6], w7 = pf[7];
                short* dx = &sAm[(tid >> 2) * SA + (tid & 3) * 64];
                *(short8*)(dx + 0)  = w0; *(short8*)(dx + 8)  = w1;
                *(short8*)(dx + 16) = w2; *(short8*)(dx + 24) = w3;
                *(short8*)(dx + 32) = w4; *(short8*)(dx + 40) = w5;
                *(short8*)(dx + 48) = w6; *(short8*)(dx + 56) = w7;
            }
            *(short8*)(dh + 0)  = h0v; *(short8*)(dh + 8)  = h1v;
            *(short8*)(dh + 16) = h2v; *(short8*)(dh + 24) = h3v;
            *(short8*)(dh + 32) = h4v; *(short8*)(dh + 40) = h5v;
            *(short8*)(dh + 48) = h6v; *(short8*)(dh + 56) = h7v;
        }
        __syncthreads();

        // ---- MFMA ----
        f32x4 ax0 = {}, ax1 = {}, ax2 = {}, ah0 = {}, ah1 = {}, ah2 = {};
        #pragma unroll
        for (int kt = 0; kt < KT; ++kt) {
            short8 a = *reinterpret_cast<const short8*>(&sAm[aoff + kt * 32]);
            if (kt < ksplit) {
                ax0 = __builtin_amdgcn_mfma_f32_16x16x32_bf16(a, Breg[0 * KT + kt], ax0, 0, 0, 0);
                ax1 = __builtin_amdgcn_mfma_f32_16x16x32_bf16(a, Breg[1 * KT + kt], ax1, 0, 0, 0);
                ax2 = __builtin_amdgcn_mfma_f32_16x16x32_bf16(a, Breg[2 * KT + kt], ax2, 0, 0, 0);
            } else {
                ah0 = __builtin_amdgcn_mfma_f32_16x16x32_bf16(a, Breg[0 * KT + kt], ah0, 0, 0, 0);
                ah1 = __builtin_amdgcn_mfma_f32_16x16x32_bf16(a, Breg[1 * KT + kt], ah1, 0, 0, 0);
                ah2 = __builtin_amdgcn_mfma_f32_16x16x32_bf16(a, Breg[2 * KT + kt], ah2, 0, 0, 0);
            }
        }

        // ---- gates + single ring store; release publishes ----
        short* rdst = ring + (l * RD + (t & 3)) * RING_ELEMS;
        float* ydst = y + (size_t)t * BB * HH;
        #pragma unroll
        for (int r = 0; r < 4; ++r) {
            int b = Mbase + 4 * q + r;
            float ho = sH[b * 17 + jj];
            float rg = sigm(ax0[r] + ah0[r] + bsr);
            float zg = sigm(ax1[r] + ah1[r] + bsz);
            float ng = tanh_f(ax2[r] + bin_ + rg * (ah2[r] + bhn_));
            float hn = ng + zg * (ho - ng);
            sH[b * 17 + jj] = hn;
            rdst[b * HH + jrow] = f2bf(hn);
            if (l == NL - 1) ydst[b * HH + jrow] = hn;
        }
        __syncthreads();             // every wave drains vmcnt before publish
        if (tid == 0)
            __hip_atomic_store(&SQF(l)[slot], t + 2, __ATOMIC_RELEASE, __HIP_MEMORY_SCOPE_AGENT);
    }

    // ---- final hidden states (fp32 from LDS) ----
    for (int i = tid; i < BB * JPC; i += 256) {
        int b = i >> 4, j2 = i & 15;
        y[(size_t)SEQ * BB * HH + (size_t)l * BB * HH + b * HH + jbase + j2] = sH[b * 17 + j2];
    }
}

extern "C" void kernel_launch(void* const* d_in, const int* in_sizes, int n_in,
                              void* d_out, int out_size, void* d_ws, size_t ws_size,
                              hipStream_t stream) {
    (void)in_sizes; (void)n_in; (void)out_size; (void)ws_size;
    const float* x         = (const float*)d_in[0];
    const float* h0        = (const float*)d_in[1];
    const float* w_ih0     = (const float*)d_in[2];
    const float* w_ih_rest = (const float*)d_in[3];
    const float* w_hh      = (const float*)d_in[4];
    const float* b_ih      = (const float*)d_in[5];
    const float* b_hh      = (const float*)d_in[6];
    float* y = (float*)d_out;

    short* ring = (short*)d_ws;
    int* flags  = (int*)((char*)d_ws + FLAGS_OFF_B);

    (void)hipMemsetAsync(flags, 0, NFLAG_INTS * sizeof(int), stream);
    // static(~71KB) + dynamic 16KB LDS > 80KB -> exactly 1 WG per CU
    gru_persist<<<256, 256, 16384, stream>>>(
        x, h0, w_ih0, w_ih_rest, w_hh, b_ih, b_hh, y, ring, flags);
}